// Round 1
// baseline (2058.314 us; speedup 1.0000x reference)
//
#include <hip/hip_runtime.h>
#include <math.h>

#define HD 64
#define G4 256   // 4*HD

__device__ __forceinline__ float sigf(float x) {
    return __builtin_amdgcn_rcpf(1.0f + __expf(-x));
}
__device__ __forceinline__ float tanh_fast(float x) {
    float ax = fabsf(x);
    float e  = __expf(-2.0f * ax);
    float t  = (1.0f - e) * __builtin_amdgcn_rcpf(1.0f + e);
    return copysignf(t, x);
}

// ---------------- Encoder: 2 stacked LSTMs over src, fused ----------------
// grid = B (512) blocks, 256 threads. Thread j owns gate-row j of both layers.
__global__ __launch_bounds__(256, 2)
void encoder_kernel(const float* __restrict__ src,
                    const float* __restrict__ w1ih, const float* __restrict__ w1hh,
                    const float* __restrict__ b1g,
                    const float* __restrict__ w2ih, const float* __restrict__ w2hh,
                    const float* __restrict__ b2g,
                    float* __restrict__ ws_h, float* __restrict__ ws_c)
{
    const int b = blockIdx.x;
    const int j = threadIdx.x;

    __shared__ float sx[3072];                 // src[b] row: 1024*3
    __shared__ __align__(16) float h1[HD];
    __shared__ __align__(16) float h2[HD];
    __shared__ float ga[G4];
    __shared__ float gb[G4];

    // stage src row (coalesced)
    {
        const float* srow = src + (size_t)b * 3072;
        for (int i = j; i < 3072; i += 256) sx[i] = srow[i];
    }

    // weights -> registers
    float wi1_0 = w1ih[j * 3 + 0], wi1_1 = w1ih[j * 3 + 1], wi1_2 = w1ih[j * 3 + 2];
    float bb1 = b1g[j], bb2 = b2g[j];
    float4 wh1[16], wi2[16], wh2[16];
    {
        const float4* p1 = (const float4*)(w1hh + (size_t)j * 64);
        const float4* p2 = (const float4*)(w2ih + (size_t)j * 64);
        const float4* p3 = (const float4*)(w2hh + (size_t)j * 64);
#pragma unroll
        for (int q = 0; q < 16; q++) { wh1[q] = p1[q]; wi2[q] = p2[q]; wh2[q] = p3[q]; }
    }

    const bool is_g = ((j >> 6) == 2);   // rows 128..191 = cell gate -> tanh
    float c1 = 0.0f, c2 = 0.0f;          // used by j < HD only
    if (j < HD) { h1[j] = 0.0f; h2[j] = 0.0f; }
    __syncthreads();

    const float4* h1v = (const float4*)h1;
    const float4* h2v = (const float4*)h2;

    for (int t = 0; t < 1024; t++) {
        // ---- layer 1: g1 = Wih1*x_t + Whh1*h1 + b1 ----
        float x0 = sx[t * 3 + 0], x1 = sx[t * 3 + 1], x2 = sx[t * 3 + 2];
        float4 a = make_float4(0.f, 0.f, 0.f, 0.f);
#pragma unroll
        for (int q = 0; q < 16; q++) {
            float4 h = h1v[q];
            a.x += wh1[q].x * h.x; a.y += wh1[q].y * h.y;
            a.z += wh1[q].z * h.z; a.w += wh1[q].w * h.w;
        }
        float g = (a.x + a.y) + (a.z + a.w);
        g += wi1_0 * x0 + wi1_1 * x1 + wi1_2 * x2 + bb1;
        ga[j] = is_g ? tanh_fast(g) : sigf(g);
        __syncthreads();

        if (j < HD) {
            float iv = ga[j], fv = ga[HD + j], gv = ga[2 * HD + j], ov = ga[3 * HD + j];
            c1 = fv * c1 + iv * gv;
            h1[j] = ov * tanh_fast(c1);
        }
        __syncthreads();

        // ---- layer 2: g2 = Wih2*h1(new) + Whh2*h2(old) + b2 ----
        float4 a2 = make_float4(0.f, 0.f, 0.f, 0.f);
#pragma unroll
        for (int q = 0; q < 16; q++) {
            float4 h = h1v[q];
            a2.x += wi2[q].x * h.x; a2.y += wi2[q].y * h.y;
            a2.z += wi2[q].z * h.z; a2.w += wi2[q].w * h.w;
        }
#pragma unroll
        for (int q = 0; q < 16; q++) {
            float4 h = h2v[q];
            a2.x += wh2[q].x * h.x; a2.y += wh2[q].y * h.y;
            a2.z += wh2[q].z * h.z; a2.w += wh2[q].w * h.w;
        }
        float g2 = (a2.x + a2.y) + (a2.z + a2.w) + bb2;
        gb[j] = is_g ? tanh_fast(g2) : sigf(g2);
        __syncthreads();

        if (j < HD) {
            float iv = gb[j], fv = gb[HD + j], gv = gb[2 * HD + j], ov = gb[3 * HD + j];
            c2 = fv * c2 + iv * gv;
            h2[j] = ov * tanh_fast(c2);
        }
        __syncthreads();
    }

    if (j < HD) {
        ws_h[(size_t)b * HD + j] = h2[j];
        ws_c[(size_t)b * HD + j] = c2;
    }
}

// ---------------- Decoder: 2 chained LSTM cells + FC head ----------------
__global__ __launch_bounds__(256, 2)
void decoder_kernel(const float* __restrict__ trg,
                    const float* __restrict__ d1ih, const float* __restrict__ d1hh,
                    const float* __restrict__ d1b,
                    const float* __restrict__ d2ih, const float* __restrict__ d2hh,
                    const float* __restrict__ d2b,
                    const float* __restrict__ fcW, const float* __restrict__ fcb,
                    const float* __restrict__ ws_h, const float* __restrict__ ws_c,
                    float* __restrict__ out)
{
    const int b = blockIdx.x;
    const int j = threadIdx.x;

    __shared__ float tx[1536];                 // trg[b] row: 512*3
    __shared__ __align__(16) float hs[HD];
    __shared__ __align__(16) float h1s[HD];
    __shared__ float ga[G4];
    __shared__ float gb[G4];

    {
        const float* trow = trg + (size_t)b * 1536;
        for (int i = j; i < 1536; i += 256) tx[i] = trow[i];
    }

    float wi1_0 = d1ih[j * 3 + 0], wi1_1 = d1ih[j * 3 + 1], wi1_2 = d1ih[j * 3 + 2];
    float bb1 = d1b[j], bb2 = d2b[j];
    float4 wh1[16], w2s[16];
    {
        const float4* p1 = (const float4*)(d1hh + (size_t)j * 64);
        const float4* pa = (const float4*)(d2ih + (size_t)j * 64);
        const float4* pb = (const float4*)(d2hh + (size_t)j * 64);
#pragma unroll
        for (int q = 0; q < 16; q++) {
            wh1[q] = p1[q];
            float4 x = pa[q], y = pb[q];
            w2s[q] = make_float4(x.x + y.x, x.y + y.y, x.z + y.z, x.w + y.w);
        }
    }

    float fw0 = 0.f, fw1 = 0.f, fw2 = 0.f;
    float fb0 = fcb[0], fb1 = fcb[1], fb2 = fcb[2];
    float c = 0.0f;
    if (j < HD) {
        fw0 = fcW[j]; fw1 = fcW[64 + j]; fw2 = fcW[128 + j];
        hs[j] = ws_h[(size_t)b * HD + j];
        c = ws_c[(size_t)b * HD + j];
    }
    const bool is_g = ((j >> 6) == 2);
    __syncthreads();

    const float4* hv  = (const float4*)hs;
    const float4* h1v = (const float4*)h1s;

    for (int t = 0; t < 511; t++) {
        // ---- dec1: g1 = Wih*x_t + Whh*h + b ----
        float x0 = tx[t * 3 + 0], x1 = tx[t * 3 + 1], x2 = tx[t * 3 + 2];
        float4 a = make_float4(0.f, 0.f, 0.f, 0.f);
#pragma unroll
        for (int q = 0; q < 16; q++) {
            float4 h = hv[q];
            a.x += wh1[q].x * h.x; a.y += wh1[q].y * h.y;
            a.z += wh1[q].z * h.z; a.w += wh1[q].w * h.w;
        }
        float g = (a.x + a.y) + (a.z + a.w);
        g += wi1_0 * x0 + wi1_1 * x1 + wi1_2 * x2 + bb1;
        ga[j] = is_g ? tanh_fast(g) : sigf(g);
        __syncthreads();

        float c1 = 0.0f;
        if (j < HD) {
            float iv = ga[j], fv = ga[HD + j], gv = ga[2 * HD + j], ov = ga[3 * HD + j];
            c1 = fv * c + iv * gv;
            h1s[j] = ov * tanh_fast(c1);
        }
        __syncthreads();

        // ---- dec2: x = h = h1  ->  g2 = (Wih2+Whh2)*h1 + b2 ----
        float4 a2 = make_float4(0.f, 0.f, 0.f, 0.f);
#pragma unroll
        for (int q = 0; q < 16; q++) {
            float4 h = h1v[q];
            a2.x += w2s[q].x * h.x; a2.y += w2s[q].y * h.y;
            a2.z += w2s[q].z * h.z; a2.w += w2s[q].w * h.w;
        }
        float g2 = (a2.x + a2.y) + (a2.z + a2.w) + bb2;
        gb[j] = is_g ? tanh_fast(g2) : sigf(g2);
        __syncthreads();

        if (j < HD) {
            float iv = gb[j], fv = gb[HD + j], gv = gb[2 * HD + j], ov = gb[3 * HD + j];
            float c2 = fv * c1 + iv * gv;
            float h2 = ov * tanh_fast(c2);
            c = c2;
            hs[j] = h2;
            // FC head: pred[d] = sum_u fcW[d][u]*h2[u] + fcb[d]
            float p0 = fw0 * h2, p1 = fw1 * h2, p2 = fw2 * h2;
#pragma unroll
            for (int off = 32; off > 0; off >>= 1) {
                p0 += __shfl_down(p0, off);
                p1 += __shfl_down(p1, off);
                p2 += __shfl_down(p2, off);
            }
            if (j == 0) {
                float* o = out + ((size_t)b * 512 + t + 1) * 3;
                o[0] = p0 + fb0; o[1] = p1 + fb1; o[2] = p2 + fb2;
            }
        }
        __syncthreads();
    }
}

extern "C" void kernel_launch(void* const* d_in, const int* in_sizes, int n_in,
                              void* d_out, int out_size, void* d_ws, size_t ws_size,
                              hipStream_t stream)
{
    const float* src    = (const float*)d_in[0];
    const float* trg    = (const float*)d_in[1];
    const float* e1ih   = (const float*)d_in[2];
    const float* e1hh   = (const float*)d_in[3];
    const float* e1b    = (const float*)d_in[4];
    const float* e2ih   = (const float*)d_in[5];
    const float* e2hh   = (const float*)d_in[6];
    const float* e2b    = (const float*)d_in[7];
    const float* dd1ih  = (const float*)d_in[8];
    const float* dd1hh  = (const float*)d_in[9];
    const float* dd1b   = (const float*)d_in[10];
    const float* dd2ih  = (const float*)d_in[11];
    const float* dd2hh  = (const float*)d_in[12];
    const float* dd2b   = (const float*)d_in[13];
    const float* fcW    = (const float*)d_in[14];
    const float* fcb    = (const float*)d_in[15];
    float* out = (float*)d_out;

    float* wsh = (float*)d_ws;            // 512*64 floats
    float* wsc = wsh + 512 * 64;          // 512*64 floats

    // outputs[:, 0, :] stays 0; decoder fills t >= 1
    hipMemsetAsync(d_out, 0, (size_t)out_size * sizeof(float), stream);

    encoder_kernel<<<512, 256, 0, stream>>>(src, e1ih, e1hh, e1b, e2ih, e2hh, e2b, wsh, wsc);
    decoder_kernel<<<512, 256, 0, stream>>>(trg, dd1ih, dd1hh, dd1b, dd2ih, dd2hh, dd2b,
                                            fcW, fcb, wsh, wsc, out);
}